// Round 5
// baseline (198.849 us; speedup 1.0000x reference)
//
#include <hip/hip_runtime.h>
#include <math.h>

#define IN_F   768
#define OUT_F  256
#define NROWS  8192
#define LALPHA 0.2f
// Rows with s1max - s1_i > CUT/(alpha*N) have softmax weight < exp(-CUT): droppable.
// r is monotone increasing in s1 (dr/ds1 >= alpha*N) and r_i - r_max <= alpha*N*(s1_i - s1max).
#define CUT    60.0f
#define GAP    (CUT / (LALPHA * 8192.0f))   // 0.0366211
#define MAXC   64
#define NBLK   1024          // 4 blocks/CU x 256 CUs -> fully resident (required by barriers)

// ---- ws layout (floats): w1[768]@0, w2[768]@768, s1[8192]@1536, s2[8192]@9728,
// ---- barrier ints @17920 (zeroed via hipMemsetAsync each launch):
//      A: groups bar[g*32] g<32, root bar[1024];  B: groups bar[1056+g*32], root bar[2080]

__device__ inline float waveReduceSum(float v) {
    for (int off = 32; off > 0; off >>= 1) v += __shfl_down(v, off, 64);
    return v;
}
__device__ inline float waveReduceMax(float v) {
    for (int off = 32; off > 0; off >>= 1) v = fmaxf(v, __shfl_down(v, off, 64));
    return v;
}
__device__ inline float blockReduceMax256(float v, float* red, int tid) {
    v = waveReduceMax(v);
    if ((tid & 63) == 0) red[tid >> 6] = v;
    __syncthreads();
    float r = fmaxf(fmaxf(red[0], red[1]), fmaxf(red[2], red[3]));
    __syncthreads();
    return r;
}

// Tree barrier: 1024 blocks -> 32 line-strided group counters -> 1 root.
// Requires all NBLK blocks resident (guaranteed by __launch_bounds__(256,4) + 39KB LDS).
// Bounded spin: on pathological non-residency we fall through (absmax fails, no hang).
__device__ inline void grid_barrier(int* groups, int* root, int bid, int tid) {
    if (tid == 0) {
        __threadfence();                               // release prior global writes
        int g = bid & 31;
        int old = __hip_atomic_fetch_add(&groups[g * 32], 1,
                                         __ATOMIC_ACQ_REL, __HIP_MEMORY_SCOPE_AGENT);
        if (old == 31)
            __hip_atomic_fetch_add(root, 1, __ATOMIC_ACQ_REL, __HIP_MEMORY_SCOPE_AGENT);
        int spins = 0;
        while (__hip_atomic_load(root, __ATOMIC_ACQUIRE, __HIP_MEMORY_SCOPE_AGENT) < 32) {
            __builtin_amdgcn_s_sleep(8);
            if (++spins > (1 << 22)) break;            // ~0.3s escape hatch
        }
    }
    __syncthreads();
}

__global__ void __launch_bounds__(256, 4)
fused_kernel(const float* __restrict__ X, const float* __restrict__ W,
             const float* __restrict__ a,
             float* __restrict__ w1, float* __restrict__ w2,
             float* __restrict__ s1g, float* __restrict__ s2g,
             int* __restrict__ bar, float* __restrict__ out) {
    __shared__ float  smem[NROWS];      // 32 KB: s2 stage in P2
    __shared__ float  smem2[2 * IN_F];  // 6 KB: 'a' in P0, w1|w2 in P1, y in P2
    __shared__ float  red[4];
    __shared__ float4 red4[4];
    __shared__ int    list[MAXC];
    __shared__ float  slist[MAXC];
    __shared__ float  rlist[MAXC];
    __shared__ float  wts[MAXC];
    __shared__ int    cnt;

    const int tid  = threadIdx.x;
    const int bid  = blockIdx.x;
    const int wid  = tid >> 6;
    const int lane = tid & 63;

    // ---------------- P0: w1 = W@a1, w2 = W@a2  (blocks 0..95, 8 k-rows each)
    if (bid < 96) {
        smem2[tid]       = a[tid];
        smem2[256 + tid] = a[256 + tid];
        __syncthreads();
        int half = tid >> 5, sub = tid & 31;
        int k = bid * 8 + half;                        // k in [0,768)
        const float* row = W + (size_t)k * OUT_F;
        float acc1 = 0.f, acc2 = 0.f;
#pragma unroll
        for (int j = 0; j < 8; ++j) {
            int f = sub + 32 * j;
            float w = row[f];
            acc1 += w * smem2[f];
            acc2 += w * smem2[256 + f];
        }
        for (int off = 16; off > 0; off >>= 1) {
            acc1 += __shfl_down(acc1, off, 32);
            acc2 += __shfl_down(acc2, off, 32);
        }
        if (sub == 0) { w1[k] = acc1; w2[k] = acc2; }
    }
    grid_barrier(bar, bar + 1024, bid, tid);

    // ---------------- P1: s1[i]=X[i]·w1, s2[i]=X[i]·w2  (8 rows/block, 2 rows/wave)
    {
        smem2[tid]        = w1[tid];
        smem2[256 + tid]  = w1[256 + tid];
        smem2[512 + tid]  = w1[512 + tid];
        smem2[768 + tid]  = w2[tid];
        smem2[1024 + tid] = w2[256 + tid];
        smem2[1280 + tid] = w2[512 + tid];
        __syncthreads();
        const float4* l1 = (const float4*)smem2;
        const float4* l2 = (const float4*)(smem2 + IN_F);
        int rA = bid * 8 + wid * 2, rB = rA + 1;
        const float4* ra = (const float4*)(X + (size_t)rA * IN_F);
        const float4* rb = (const float4*)(X + (size_t)rB * IN_F);
        float a1 = 0.f, a2 = 0.f, b1 = 0.f, b2 = 0.f;
#pragma unroll
        for (int c0 = 0; c0 < 3; ++c0) {
            int c = lane + 64 * c0;
            float4 xa = ra[c], xb = rb[c];
            float4 u = l1[c], v = l2[c];
            a1 += xa.x * u.x + xa.y * u.y + xa.z * u.z + xa.w * u.w;
            a2 += xa.x * v.x + xa.y * v.y + xa.z * v.z + xa.w * v.w;
            b1 += xb.x * u.x + xb.y * u.y + xb.z * u.z + xb.w * u.w;
            b2 += xb.x * v.x + xb.y * v.y + xb.z * v.z + xb.w * v.w;
        }
        a1 = waveReduceSum(a1); a2 = waveReduceSum(a2);
        b1 = waveReduceSum(b1); b2 = waveReduceSum(b2);
        if (lane == 0) { s1g[rA] = a1; s2g[rA] = a2; s1g[rB] = b1; s2g[rB] = b2; }
    }
    grid_barrier(bar + 1056, bar + 2080, bid, tid);

    // ---------------- P2: candidates + softmax + y + out matvec  (blocks 0..63)
    if (bid >= 64) return;
    if (tid == 0) cnt = 0;

    float4 rv[8];
    float lmax = -INFINITY;
#pragma unroll
    for (int p = 0; p < 8; ++p) {
        rv[p] = ((const float4*)s1g)[tid + 256 * p];
        float4 v2 = ((const float4*)s2g)[tid + 256 * p];
        ((float4*)smem)[tid + 256 * p] = v2;
        lmax = fmaxf(lmax, fmaxf(fmaxf(rv[p].x, rv[p].y), fmaxf(rv[p].z, rv[p].w)));
    }
    float s1max = blockReduceMax256(lmax, red, tid);   // internal syncs fence staging+cnt
    float thr = s1max - GAP;

#pragma unroll
    for (int p = 0; p < 8; ++p) {
        int base = 4 * (tid + 256 * p);
        float v[4] = { rv[p].x, rv[p].y, rv[p].z, rv[p].w };
#pragma unroll
        for (int q = 0; q < 4; ++q) {
            if (v[q] >= thr) {
                int pos = atomicAdd(&cnt, 1);
                if (pos < MAXC) { list[pos] = base + q; slist[pos] = v[q]; }
            }
        }
    }
    __syncthreads();
    int n = cnt < MAXC ? cnt : MAXC;
    if (tid == 0 && n > 1) {                           // deterministic order
        for (int i = 1; i < n; ++i) {
            int ki = list[i]; float kv = slist[i]; int j = i - 1;
            while (j >= 0 && list[j] > ki) {
                list[j + 1] = list[j]; slist[j + 1] = slist[j]; --j;
            }
            list[j + 1] = ki; slist[j + 1] = kv;
        }
    }
    __syncthreads();

    if (n > 1) {                                       // exact r per candidate
        for (int c = wid; c < n; c += 4) {
            float s1c = slist[c];
            float acc = 0.f;
#pragma unroll 4
            for (int q = lane; q < NROWS / 4; q += 64) {
                float4 v = ((const float4*)smem)[q];
                acc += fmaxf(s1c + v.x, 0.f) + fmaxf(s1c + v.y, 0.f)
                     + fmaxf(s1c + v.z, 0.f) + fmaxf(s1c + v.w, 0.f);
            }
            acc = waveReduceSum(acc);
            if (lane == 0)
                rlist[c] = LALPHA * 8192.f * s1c + (1.f - LALPHA) * acc;
        }
    }
    __syncthreads();
    if (tid == 0) {
        if (n == 1) wts[0] = 1.0f;
        else {
            float M = -INFINITY;
            for (int c = 0; c < n; ++c) M = fmaxf(M, rlist[c]);
            float Z = 0.f;
            for (int c = 0; c < n; ++c) { float e = expf(rlist[c] - M); rlist[c] = e; Z += e; }
            float invZ = 1.0f / Z;
            for (int c = 0; c < n; ++c) wts[c] = rlist[c] * invZ;
        }
    }
    __syncthreads();

    float* y = smem2;                                  // reuse (post-sync)
    for (int p = tid; p < IN_F; p += 256) {
        float acc = 0.f;
        for (int c = 0; c < n; ++c)
            acc += wts[c] * X[(size_t)list[c] * IN_F + p];
        y[p] = acc;
    }
    __syncthreads();

    int b4 = blockIdx.x * 4;
    float4 acc = make_float4(0.f, 0.f, 0.f, 0.f);
#pragma unroll
    for (int j = 0; j < 3; ++j) {
        int k = tid + 256 * j;
        float4 w = *(const float4*)(W + (size_t)k * OUT_F + b4);
        float yk = y[k];
        acc.x += yk * w.x; acc.y += yk * w.y; acc.z += yk * w.z; acc.w += yk * w.w;
    }
    for (int off = 32; off > 0; off >>= 1) {
        acc.x += __shfl_down(acc.x, off, 64);
        acc.y += __shfl_down(acc.y, off, 64);
        acc.z += __shfl_down(acc.z, off, 64);
        acc.w += __shfl_down(acc.w, off, 64);
    }
    if (lane == 0) red4[wid] = acc;
    __syncthreads();
    if (tid == 0) {
        float4 t;
        t.x = red4[0].x + red4[1].x + red4[2].x + red4[3].x;
        t.y = red4[0].y + red4[1].y + red4[2].y + red4[3].y;
        t.z = red4[0].z + red4[1].z + red4[2].z + red4[3].z;
        t.w = red4[0].w + red4[1].w + red4[2].w + red4[3].w;
        out[b4 + 0] = (t.x > 0.f) ? t.x : (expf(t.x) - 1.0f);
        out[b4 + 1] = (t.y > 0.f) ? t.y : (expf(t.y) - 1.0f);
        out[b4 + 2] = (t.z > 0.f) ? t.z : (expf(t.z) - 1.0f);
        out[b4 + 3] = (t.w > 0.f) ? t.w : (expf(t.w) - 1.0f);
    }
}

extern "C" void kernel_launch(void* const* d_in, const int* in_sizes, int n_in,
                              void* d_out, int out_size, void* d_ws, size_t ws_size,
                              hipStream_t stream) {
    const float* X = (const float*)d_in[0];   // [8192, 768]
    const float* W = (const float*)d_in[1];   // [768, 256]
    const float* a = (const float*)d_in[2];   // [512, 1]
    float* out = (float*)d_out;               // [256]

    float* ws = (float*)d_ws;
    float* w1 = ws;            // 768
    float* w2 = ws + 768;      // 768
    float* s1 = ws + 1536;     // 8192
    float* s2 = ws + 9728;     // 8192
    int*   bar = (int*)(ws + 17920);  // 2304 ints of barrier state

    hipMemsetAsync(bar, 0, 2304 * sizeof(int), stream);
    fused_kernel<<<NBLK, 256, 0, stream>>>(X, W, a, w1, w2, s1, s2, bar, out);
}

// Round 6
// 79.202 us; speedup vs baseline: 2.5107x; 2.5107x over previous
//
#include <hip/hip_runtime.h>
#include <math.h>

#define IN_F   768
#define OUT_F  256
#define NROWS  8192
#define LALPHA 0.2f
// Rows with s1max - s1_i > CUT/(alpha*N) have softmax weight < exp(-CUT): droppable.
// r is monotone increasing in s1 (dr/ds1 >= alpha*N) and r_i - r_max <= alpha*N*(s1_i - s1max).
#define CUT    60.0f
#define GAP    (CUT / (LALPHA * 8192.0f))   // 0.0366211
#define MAXC   64

// ---- workspace layout (floats): w1[768]@0, w2[768]@768, s1[8192]@1536, s2[8192]@9728
// NOTE (R5 lesson): grid-wide sync on MI355X costs 30-70us in ANY form (cg::sync or
// hand-rolled agent-scope barrier -> L2-invalidate storms across 8 XCDs). Three graph
// nodes with ~2-3us boundaries beat single-kernel fusion. Do not re-fuse.

__device__ inline float waveReduceSum(float v) {
    for (int off = 32; off > 0; off >>= 1) v += __shfl_down(v, off, 64);
    return v;
}
__device__ inline float waveReduceMax(float v) {
    for (int off = 32; off > 0; off >>= 1) v = fmaxf(v, __shfl_down(v, off, 64));
    return v;
}
__device__ inline float blockReduceMax256(float v, float* red, int tid) {
    v = waveReduceMax(v);
    if ((tid & 63) == 0) red[tid >> 6] = v;
    __syncthreads();
    float r = fmaxf(fmaxf(red[0], red[1]), fmaxf(red[2], red[3]));
    __syncthreads();
    return r;
}

// K0: w1 = W @ a[:256], w2 = W @ a[256:].  grid=96, block=256.
__global__ __launch_bounds__(256) void wvec_kernel(const float* __restrict__ W,
                                                   const float* __restrict__ a,
                                                   float* __restrict__ w1,
                                                   float* __restrict__ w2) {
    __shared__ float la[2 * OUT_F];
    int tid = threadIdx.x;
    la[tid]       = a[tid];
    la[256 + tid] = a[256 + tid];
    __syncthreads();
    int half = tid >> 5;                 // 0..7 : row within block
    int sub  = tid & 31;
    int k = blockIdx.x * 8 + half;       // k in [0,768)
    const float* row = W + (size_t)k * OUT_F;
    float acc1 = 0.f, acc2 = 0.f;
#pragma unroll
    for (int j = 0; j < 8; ++j) {
        int f = sub + 32 * j;
        float w = row[f];
        acc1 += w * la[f];
        acc2 += w * la[256 + f];
    }
    for (int off = 16; off > 0; off >>= 1) {
        acc1 += __shfl_down(acc1, off, 32);
        acc2 += __shfl_down(acc2, off, 32);
    }
    if (sub == 0) { w1[k] = acc1; w2[k] = acc2; }
}

// K1: s1[i] = X[i]·w1, s2[i] = X[i]·w2.  Two rows per wave. grid=1024, block=256.
// 6 independent float4 loads in flight per lane (deeper MLP than 1-row/wave).
__global__ __launch_bounds__(256) void s1s2_kernel(const float* __restrict__ X,
                                                   const float* __restrict__ w1,
                                                   const float* __restrict__ w2,
                                                   float* __restrict__ s1,
                                                   float* __restrict__ s2) {
    __shared__ float lw[IN_F * 2];
    int tid = threadIdx.x;
    for (int p = tid; p < IN_F; p += 256) { lw[p] = w1[p]; lw[IN_F + p] = w2[p]; }
    __syncthreads();
    int wid = tid >> 6, lane = tid & 63;
    int rA = blockIdx.x * 8 + wid * 2, rB = rA + 1;    // rows in [0,8192)
    const float4* ra = (const float4*)(X + (size_t)rA * IN_F);
    const float4* rb = (const float4*)(X + (size_t)rB * IN_F);
    const float4* l1 = (const float4*)lw;
    const float4* l2 = (const float4*)(lw + IN_F);
    float a1 = 0.f, a2 = 0.f, b1 = 0.f, b2 = 0.f;
#pragma unroll
    for (int c0 = 0; c0 < 3; ++c0) {
        int c = lane + 64 * c0;
        float4 xa = ra[c], xb = rb[c];
        float4 u = l1[c], v = l2[c];
        a1 += xa.x * u.x + xa.y * u.y + xa.z * u.z + xa.w * u.w;
        a2 += xa.x * v.x + xa.y * v.y + xa.z * v.z + xa.w * v.w;
        b1 += xb.x * u.x + xb.y * u.y + xb.z * u.z + xb.w * u.w;
        b2 += xb.x * v.x + xb.y * v.y + xb.z * v.z + xb.w * v.w;
    }
    a1 = waveReduceSum(a1); a2 = waveReduceSum(a2);
    b1 = waveReduceSum(b1); b2 = waveReduceSum(b2);
    if (lane == 0) { s1[rA] = a1; s2[rA] = a2; s1[rB] = b1; s2[rB] = b2; }
}

// K2: candidates + softmax + weighted row + output matvec, redundantly per block.
// grid=64, block=256; block b writes out[4b..4b+4).
__global__ __launch_bounds__(256) void finale_kernel(const float* __restrict__ X,
                                                     const float* __restrict__ W,
                                                     const float* __restrict__ s1g,
                                                     const float* __restrict__ s2g,
                                                     float* __restrict__ out) {
    __shared__ float  s2[NROWS];       // 32 KB
    __shared__ float  y[IN_F];         // 3 KB
    __shared__ float  red[4];
    __shared__ float4 red4[4];
    __shared__ int    list[MAXC];
    __shared__ float  slist[MAXC];     // candidate s1 values
    __shared__ float  rlist[MAXC];     // candidate r
    __shared__ float  wts[MAXC];       // normalized softmax weights
    __shared__ int    cnt;
    int tid = threadIdx.x;
    int wid = tid >> 6, lane = tid & 63;
    if (tid == 0) cnt = 0;

    // s1 -> registers (for max + scan), s2 -> LDS
    float4 rv[8];
    float lmax = -INFINITY;
#pragma unroll
    for (int p = 0; p < 8; ++p) {
        rv[p] = ((const float4*)s1g)[tid + 256 * p];
        float4 v2 = ((const float4*)s2g)[tid + 256 * p];
        ((float4*)s2)[tid + 256 * p] = v2;
        lmax = fmaxf(lmax, fmaxf(fmaxf(rv[p].x, rv[p].y), fmaxf(rv[p].z, rv[p].w)));
    }
    // blockReduceMax's internal sync also fences the s2 staging + cnt init
    float s1max = blockReduceMax256(lmax, red, tid);
    float thr = s1max - GAP;

    // candidate scan from registers
#pragma unroll
    for (int p = 0; p < 8; ++p) {
        int base = 4 * (tid + 256 * p);
        float v[4] = { rv[p].x, rv[p].y, rv[p].z, rv[p].w };
#pragma unroll
        for (int q = 0; q < 4; ++q) {
            if (v[q] >= thr) {
                int pos = atomicAdd(&cnt, 1);
                if (pos < MAXC) { list[pos] = base + q; slist[pos] = v[q]; }
            }
        }
    }
    __syncthreads();
    int n = cnt < MAXC ? cnt : MAXC;
    if (tid == 0 && n > 1) {           // deterministic order (atomic order varies)
        for (int i = 1; i < n; ++i) {
            int ki = list[i]; float kv = slist[i]; int j = i - 1;
            while (j >= 0 && list[j] > ki) {
                list[j + 1] = list[j]; slist[j + 1] = slist[j]; --j;
            }
            list[j + 1] = ki; slist[j + 1] = kv;
        }
    }
    __syncthreads();

    // exact r per candidate (wave-parallel).  alpha*S_total shift dropped: softmax-invariant.
    if (n > 1) {
        for (int c = wid; c < n; c += 4) {
            float s1c = slist[c];
            float acc = 0.f;
#pragma unroll 4
            for (int q = lane; q < NROWS / 4; q += 64) {   // 32 float4 per lane
                float4 v = ((const float4*)s2)[q];
                acc += fmaxf(s1c + v.x, 0.f) + fmaxf(s1c + v.y, 0.f)
                     + fmaxf(s1c + v.z, 0.f) + fmaxf(s1c + v.w, 0.f);
            }
            acc = waveReduceSum(acc);
            if (lane == 0)
                rlist[c] = LALPHA * 8192.f * s1c + (1.f - LALPHA) * acc;
        }
    }
    __syncthreads();
    if (tid == 0) {
        if (n == 1) wts[0] = 1.0f;
        else {
            float M = -INFINITY;
            for (int c = 0; c < n; ++c) M = fmaxf(M, rlist[c]);
            float Z = 0.f;
            for (int c = 0; c < n; ++c) { float e = expf(rlist[c] - M); rlist[c] = e; Z += e; }
            float invZ = 1.0f / Z;
            for (int c = 0; c < n; ++c) wts[c] = rlist[c] * invZ;
        }
    }
    __syncthreads();

    // y = sum_c wts[c] * X[idx_c]
    for (int p = tid; p < IN_F; p += 256) {
        float acc = 0.f;
        for (int c = 0; c < n; ++c)
            acc += wts[c] * X[(size_t)list[c] * IN_F + p];
        y[p] = acc;
    }
    __syncthreads();

    // out[4b..4b+4) = elu( y · W[:, 4b..4b+4) );  W rows read as float4 (coalesced lines)
    int b4 = blockIdx.x * 4;
    float4 acc = make_float4(0.f, 0.f, 0.f, 0.f);
#pragma unroll
    for (int j = 0; j < 3; ++j) {
        int k = tid + 256 * j;
        float4 w = *(const float4*)(W + (size_t)k * OUT_F + b4);
        float yk = y[k];
        acc.x += yk * w.x; acc.y += yk * w.y; acc.z += yk * w.z; acc.w += yk * w.w;
    }
    for (int off = 32; off > 0; off >>= 1) {
        acc.x += __shfl_down(acc.x, off, 64);
        acc.y += __shfl_down(acc.y, off, 64);
        acc.z += __shfl_down(acc.z, off, 64);
        acc.w += __shfl_down(acc.w, off, 64);
    }
    if (lane == 0) red4[wid] = acc;
    __syncthreads();
    if (tid == 0) {
        float4 t;
        t.x = red4[0].x + red4[1].x + red4[2].x + red4[3].x;
        t.y = red4[0].y + red4[1].y + red4[2].y + red4[3].y;
        t.z = red4[0].z + red4[1].z + red4[2].z + red4[3].z;
        t.w = red4[0].w + red4[1].w + red4[2].w + red4[3].w;
        out[b4 + 0] = (t.x > 0.f) ? t.x : (expf(t.x) - 1.0f);
        out[b4 + 1] = (t.y > 0.f) ? t.y : (expf(t.y) - 1.0f);
        out[b4 + 2] = (t.z > 0.f) ? t.z : (expf(t.z) - 1.0f);
        out[b4 + 3] = (t.w > 0.f) ? t.w : (expf(t.w) - 1.0f);
    }
}

extern "C" void kernel_launch(void* const* d_in, const int* in_sizes, int n_in,
                              void* d_out, int out_size, void* d_ws, size_t ws_size,
                              hipStream_t stream) {
    const float* X = (const float*)d_in[0];   // [8192, 768]
    const float* W = (const float*)d_in[1];   // [768, 256]
    const float* a = (const float*)d_in[2];   // [512, 1]
    float* out = (float*)d_out;               // [256]

    float* ws = (float*)d_ws;
    float* w1 = ws;            // 768
    float* w2 = ws + 768;      // 768
    float* s1 = ws + 1536;     // 8192
    float* s2 = ws + 9728;     // 8192

    wvec_kernel<<<96, 256, 0, stream>>>(W, a, w1, w2);
    s1s2_kernel<<<1024, 256, 0, stream>>>(X, w1, w2, s1, s2);
    finale_kernel<<<64, 256, 0, stream>>>(X, W, s1, s2, out);
}